// Round 11
// baseline (17633.408 us; speedup 1.0000x reference)
//
#include <hip/hip_runtime.h>

#define NNODE 101
#define DIM   128
#define NHEAD 8
#define NSTEP 150
#define BTOT  2048
#define ENCP  132          // padded enc row stride in LDS

// packed-weight ws layout (floats)
#define OFF_FCP   0
#define OFF_FC1P  16384
#define OFF_MWP   32768
#define OFF_MVP   49152
#define OFF_FP    65536
#define OFF_MKP   81920
#define OFF_FCC   98304
#define NORM_PROB 0.08838834764831845f

// One block = TWO batch elements, 512 threads (8 waves), 1 block/CU (LDS 141 KB).
// R10 + (a) PH3/PH5 enc reads moved from the saturated LDS pipe to global/L2
// (enc slice is L2-resident; values identical, chains bit-exact); (b) tail merge:
// logits+argmax+state+mask fused into one per-elem wave phase (-2 barriers).
struct __align__(16) BS {
  float enc[2][NNODE * ENCP];           // 2 x 53328 B (used by init, PH7, PH9)
  float in_[2][DIM], pl[2][DIM], dec[2][DIM], q[2][DIM], attn[2][DIM], op[2][DIM];
  float U[2][1888];                     // QK/ZR: h*132+i ; CMP: 1056+h*104+n
  float sc[2][1212];                    // SC: n*12+h ; SRED: n*12+k
  float mask[2][NNODE], mask1[2][NNODE], dem[2][NNODE];
  float cap[2], lp[2];
  int   idx[2];
};

#define EL(e,n,i)     S.enc[e][(n)*ENCP + (i)]
#define QK(e,h,i)     S.U[e][(h)*132 + (i)]
#define ZR(e,h,i)     S.U[e][(h)*132 + (i)]
#define CMP(e,h,n)    S.U[e][1056 + (h)*104 + (n)]
#define SC(e,n,h)     S.sc[e][(n)*12 + (h)]
#define SRED(e,n,k)   S.sc[e][(n)*12 + (k)]

// Pack all weights as float4 panels: P[i4*128 + j] = {wT[i4*4+0][j], .., wT[i4*4+3][j]}
__global__ void prep_weights(const float* __restrict__ fc_w,
                             const float* __restrict__ fc1_w,
                             const float* __restrict__ mw_w,
                             const float* __restrict__ mv_w,
                             const float* __restrict__ mfc_w,
                             const float* __restrict__ pk_w,
                             const float* __restrict__ mk_w,
                             float* __restrict__ ws) {
  int x = blockIdx.x * 256 + threadIdx.x;
  if (x < 4096) {                      // fcP
    int i4 = x >> 7, j = x & 127;
    float4 v = make_float4(fc_w[j * 129 + i4 * 4 + 0], fc_w[j * 129 + i4 * 4 + 1],
                           fc_w[j * 129 + i4 * 4 + 2], fc_w[j * 129 + i4 * 4 + 3]);
    *(float4*)&ws[OFF_FCP + x * 4] = v; return;
  }
  x -= 4096;
  if (x < 4096) {                      // fc1P
    int i4 = x >> 7, j = x & 127;
    float4 v = make_float4(fc1_w[j * 128 + i4 * 4 + 0], fc1_w[j * 128 + i4 * 4 + 1],
                           fc1_w[j * 128 + i4 * 4 + 2], fc1_w[j * 128 + i4 * 4 + 3]);
    *(float4*)&ws[OFF_FC1P + x * 4] = v; return;
  }
  x -= 4096;
  if (x < 4096) {                      // mwP
    int i4 = x >> 7, j = x & 127;
    float4 v = make_float4(mw_w[j * 128 + i4 * 4 + 0], mw_w[j * 128 + i4 * 4 + 1],
                           mw_w[j * 128 + i4 * 4 + 2], mw_w[j * 128 + i4 * 4 + 3]);
    *(float4*)&ws[OFF_MWP + x * 4] = v; return;
  }
  x -= 4096;
  if (x < 4096) {                      // mvP
    int i4 = x >> 7, j = x & 127;
    float4 v = make_float4(mv_w[j * 128 + i4 * 4 + 0], mv_w[j * 128 + i4 * 4 + 1],
                           mv_w[j * 128 + i4 * 4 + 2], mv_w[j * 128 + i4 * 4 + 3]);
    *(float4*)&ws[OFF_MVP + x * 4] = v; return;
  }
  x -= 4096;
  if (x < 4096) {                      // FP : F[i2][j] = sum_d mfc[d][i2]*pk[d][j]
    int i4 = x >> 7, j = x & 127;
    float a[4] = {0.f, 0.f, 0.f, 0.f};
    for (int d = 0; d < 128; ++d) {
      float p = pk_w[d * 128 + j];
      a[0] = fmaf(mfc_w[d * 128 + i4 * 4 + 0], p, a[0]);
      a[1] = fmaf(mfc_w[d * 128 + i4 * 4 + 1], p, a[1]);
      a[2] = fmaf(mfc_w[d * 128 + i4 * 4 + 2], p, a[2]);
      a[3] = fmaf(mfc_w[d * 128 + i4 * 4 + 3], p, a[3]);
    }
    *(float4*)&ws[OFF_FP + x * 4] = make_float4(a[0], a[1], a[2], a[3]); return;
  }
  x -= 4096;
  if (x < 4096) {                      // mkP
    int hk = x >> 7, j = x & 127;
    int h = hk >> 2, k4 = hk & 3;
    float4 v = make_float4(mk_w[(h * 16 + k4 * 4 + 0) * 128 + j],
                           mk_w[(h * 16 + k4 * 4 + 1) * 128 + j],
                           mk_w[(h * 16 + k4 * 4 + 2) * 128 + j],
                           mk_w[(h * 16 + k4 * 4 + 3) * 128 + j]);
    *(float4*)&ws[OFF_MKP + x * 4] = v; return;
  }
  x -= 4096;
  if (x < 128) ws[OFF_FCC + x] = fc_w[x * 129 + 128];   // fc cap column
}

__global__ __launch_bounds__(512, 2) void decoder_loop(
    const float* __restrict__ enc, const float* __restrict__ pool,
    const float* __restrict__ capcity, const float* __restrict__ demand,
    const float* __restrict__ ws, float* __restrict__ d_out) {
  const float4* fcP  = (const float4*)(ws + OFF_FCP);
  const float4* fc1P = (const float4*)(ws + OFF_FC1P);
  const float4* mwP  = (const float4*)(ws + OFF_MWP);
  const float4* mvP  = (const float4*)(ws + OFF_MVP);
  const float4* FP   = (const float4*)(ws + OFF_FP);
  const float4* mkP  = (const float4*)(ws + OFF_MKP);

  __shared__ BS S;

  const int tl   = threadIdx.x;       // 0..511
  const int j    = tl & 127;
  const int quad = tl >> 7;           // 0..3, wave-uniform
  const int e    = quad >> 1;         // elem for per-elem (enc) phases
  const int sub  = tl & 255;          // 0..255 within elem group
  const int b    = blockIdx.x;
  const int myb  = 2 * b + e;
  const float* encG = enc + (size_t)myb * NNODE * DIM;   // global enc base for my elem
  const float NEG_INF = -__builtin_inff();
  const float cap0 = capcity[0];

  // ---- stage both enc slices into LDS (for init, PH7, PH9) ----
  for (int ee = 0; ee < 2; ++ee) {
    const float* src = enc + (size_t)(2 * b + ee) * NNODE * DIM;
    for (int x = tl; x < NNODE * 32; x += 512) {
      int n = x >> 5, c = x & 31;
      *(float4*)&EL(ee, n, c * 4) = *(const float4*)(src + (size_t)n * DIM + c * 4);
    }
  }
  __syncthreads();

  // ---- init carry ----
  if (sub < 128) {
    S.in_[e][sub] = EL(e, 0, sub);
    S.pl[e][sub]  = pool[(size_t)myb * DIM + sub];
  }
  if (sub < NNODE) S.dem[e][sub] = demand[(size_t)myb * NNODE + sub];
  if (sub == 0) { S.cap[e] = capcity[myb]; S.lp[e] = 0.f; S.idx[e] = 0; }
  __syncthreads();
  if (sub < NNODE) {
    float v1 = (sub == 0) ? 1.f : 0.f;
    S.mask1[e][sub] = v1;
    S.mask[e][sub] = (S.dem[e][sub] > S.cap[e]) ? 1.f : v1;
  }
  __syncthreads();
  if (sub < 64) {
    bool ok = (sub == 0) || (S.mask[e][sub] > 0.5f);
    if (sub + 64 < NNODE) ok = ok && (S.mask[e][sub + 64] > 0.5f);
    bool alld = __all(ok);
    if (alld && sub == 0) S.mask[e][0] = 0.f;
  }
  __syncthreads();

  for (int step = 0; step < NSTEP; ++step) {
    const float capR0 = S.cap[0], capR1 = S.cap[1];

    // PH1: q0: fc chains (both elems); q1: fc1 chains (both elems). Packed dwordx4 loads.
    float A0 = 0.f, A1 = 0.f;
    if (quad == 0) {
      const float4* x0 = (const float4*)&S.in_[0][0];
      const float4* x1 = (const float4*)&S.in_[1][0];
      #pragma unroll 8
      for (int t = 0; t < 32; ++t) {
        float4 v0 = x0[t], v1 = x1[t];
        float4 wv = fcP[t * 128 + j];
        A0 = fmaf(v0.x, wv.x, A0); A0 = fmaf(v0.y, wv.y, A0);
        A0 = fmaf(v0.z, wv.z, A0); A0 = fmaf(v0.w, wv.w, A0);
        A1 = fmaf(v1.x, wv.x, A1); A1 = fmaf(v1.y, wv.y, A1);
        A1 = fmaf(v1.z, wv.z, A1); A1 = fmaf(v1.w, wv.w, A1);
      }
      float wc = ws[OFF_FCC + j];
      A0 = fmaf(capR0, wc, A0);
      A1 = fmaf(capR1, wc, A1);
    } else if (quad == 1) {
      const float4* x0 = (const float4*)&S.pl[0][0];
      const float4* x1 = (const float4*)&S.pl[1][0];
      #pragma unroll 8
      for (int t = 0; t < 32; ++t) {
        float4 v0 = x0[t], v1 = x1[t];
        float4 wv = fc1P[t * 128 + j];
        A0 = fmaf(v0.x, wv.x, A0); A0 = fmaf(v0.y, wv.y, A0);
        A0 = fmaf(v0.z, wv.z, A0); A0 = fmaf(v0.w, wv.w, A0);
        A1 = fmaf(v1.x, wv.x, A1); A1 = fmaf(v1.y, wv.y, A1);
        A1 = fmaf(v1.z, wv.z, A1); A1 = fmaf(v1.w, wv.w, A1);
      }
    }
    __syncthreads();
    if (quad == 0)      { S.dec[0][j] = A0; S.dec[1][j] = A1; }
    else if (quad == 1) { S.pl[0][j]  = A0; S.pl[1][j]  = A1; }
    __syncthreads();

    // PH2: q2: Q = (dec+pl) @ mw^T, both elems
    if (quad == 2) {
      const float4* d0 = (const float4*)&S.dec[0][0];
      const float4* p0 = (const float4*)&S.pl[0][0];
      const float4* d1 = (const float4*)&S.dec[1][0];
      const float4* p1 = (const float4*)&S.pl[1][0];
      float B0 = 0.f, B1 = 0.f;
      #pragma unroll 8
      for (int t = 0; t < 32; ++t) {
        float4 a0 = d0[t], b0 = p0[t], a1 = d1[t], b1 = p1[t];
        float4 wv = mwP[t * 128 + j];
        B0 = fmaf(a0.x + b0.x, wv.x, B0); B0 = fmaf(a0.y + b0.y, wv.y, B0);
        B0 = fmaf(a0.z + b0.z, wv.z, B0); B0 = fmaf(a0.w + b0.w, wv.w, B0);
        B1 = fmaf(a1.x + b1.x, wv.x, B1); B1 = fmaf(a1.y + b1.y, wv.y, B1);
        B1 = fmaf(a1.z + b1.z, wv.z, B1); B1 = fmaf(a1.w + b1.w, wv.w, B1);
      }
      S.q[0][j] = B0; S.q[1][j] = B1;
    }
    __syncthreads();

    // PH2b: quad -> heads {2q, 2q+1}; each thread computes BOTH elems per head.
    {
      const float4* q40 = (const float4*)&S.q[0][0];
      const float4* q41 = (const float4*)&S.q[1][0];
      #pragma unroll
      for (int hh = 0; hh < 2; ++hh) {
        int h = quad * 2 + hh;
        const float4* mp = mkP + (h * 4) * 128 + j;
        float4 M0 = mp[0], M1 = mp[128], M2 = mp[256], M3 = mp[384];
        float4 qa0 = q40[h*4], qb0 = q40[h*4+1], qc0 = q40[h*4+2], qd0 = q40[h*4+3];
        float4 qa1 = q41[h*4], qb1 = q41[h*4+1], qc1 = q41[h*4+2], qd1 = q41[h*4+3];
        float acc0 = 0.f, acc1 = 0.f;
        acc0 = fmaf(qa0.x, M0.x, acc0); acc0 = fmaf(qa0.y, M0.y, acc0);
        acc0 = fmaf(qa0.z, M0.z, acc0); acc0 = fmaf(qa0.w, M0.w, acc0);
        acc0 = fmaf(qb0.x, M1.x, acc0); acc0 = fmaf(qb0.y, M1.y, acc0);
        acc0 = fmaf(qb0.z, M1.z, acc0); acc0 = fmaf(qb0.w, M1.w, acc0);
        acc0 = fmaf(qc0.x, M2.x, acc0); acc0 = fmaf(qc0.y, M2.y, acc0);
        acc0 = fmaf(qc0.z, M2.z, acc0); acc0 = fmaf(qc0.w, M2.w, acc0);
        acc0 = fmaf(qd0.x, M3.x, acc0); acc0 = fmaf(qd0.y, M3.y, acc0);
        acc0 = fmaf(qd0.z, M3.z, acc0); acc0 = fmaf(qd0.w, M3.w, acc0);
        acc1 = fmaf(qa1.x, M0.x, acc1); acc1 = fmaf(qa1.y, M0.y, acc1);
        acc1 = fmaf(qa1.z, M0.z, acc1); acc1 = fmaf(qa1.w, M0.w, acc1);
        acc1 = fmaf(qb1.x, M1.x, acc1); acc1 = fmaf(qb1.y, M1.y, acc1);
        acc1 = fmaf(qb1.z, M1.z, acc1); acc1 = fmaf(qb1.w, M1.w, acc1);
        acc1 = fmaf(qc1.x, M2.x, acc1); acc1 = fmaf(qc1.y, M2.y, acc1);
        acc1 = fmaf(qc1.z, M2.z, acc1); acc1 = fmaf(qc1.w, M2.w, acc1);
        acc1 = fmaf(qd1.x, M3.x, acc1); acc1 = fmaf(qd1.y, M3.y, acc1);
        acc1 = fmaf(qd1.z, M3.z, acc1); acc1 = fmaf(qd1.w, M3.w, acc1);
        QK(0, h, j) = acc0;
        QK(1, h, j) = acc1;
      }
    }
    __syncthreads();

    // PH3: comp[h][n] = 0.25 * enc[n].qk[h] — enc from GLOBAL (L2), qk from LDS.
    // Same mapping and chain order as R10 (bit-exact; identical values).
    {
      int h = sub & 7, nb = sub >> 3;   // nb 0..31
      float acc[4] = {0.f, 0.f, 0.f, 0.f};
      #pragma unroll 4
      for (int i4 = 0; i4 < 32; ++i4) {
        float4 qv = *(const float4*)&QK(e, h, i4 * 4);
        #pragma unroll
        for (int p = 0; p < 4; ++p) {
          int n = p * 32 + nb;
          if (n < NNODE) {
            float4 e4 = *(const float4*)(encG + (size_t)n * DIM + i4 * 4);
            acc[p] = fmaf(e4.x, qv.x, acc[p]);
            acc[p] = fmaf(e4.y, qv.y, acc[p]);
            acc[p] = fmaf(e4.z, qv.z, acc[p]);
            acc[p] = fmaf(e4.w, qv.w, acc[p]);
          }
        }
      }
      #pragma unroll
      for (int p = 0; p < 4; ++p) {
        int n = p * 32 + nb;
        if (n < NNODE)
          CMP(e, h, n) = (S.mask[e][n] > 0.5f) ? NEG_INF : 0.25f * acc[p];
      }
    }
    __syncthreads();

    // PH4: softmax; 8 waves = (elem, head pair)
    {
      int w = tl >> 6, lane = tl & 63;
      int ee = w >> 2, hb = (w & 3) * 2;
      #pragma unroll
      for (int hh = 0; hh < 2; ++hh) {
        int h = hb + hh;
        float v0 = CMP(ee, h, lane);
        float v1 = (lane < NNODE - 64) ? CMP(ee, h, lane + 64) : NEG_INF;
        float m = fmaxf(v0, v1);
        #pragma unroll
        for (int o = 32; o > 0; o >>= 1) m = fmaxf(m, __shfl_xor(m, o, 64));
        float e0 = expf(v0 - m);
        float e1 = (lane < NNODE - 64) ? expf(v1 - m) : 0.f;
        float ss = e0 + e1;
        #pragma unroll
        for (int o = 32; o > 0; o >>= 1) ss += __shfl_xor(ss, o, 64);
        SC(ee, lane, h) = e0 / ss;
        if (lane < NNODE - 64) SC(ee, lane + 64, h) = e1 / ss;
      }
    }
    __syncthreads();

    // PH5: 2 waves per elem. Thread = (hq, j2): 4 heads x 2 dims.
    // sc b128 from LDS (broadcast); enc float2 from GLOBAL (perfectly coalesced).
    // Chains per (h,j): n ascending — bit-exact vs R10.
    if (sub < 128) {
      int j2 = sub & 63, hq = sub >> 6;
      int hb = hq * 4;
      float a00 = 0.f, a01 = 0.f, a10 = 0.f, a11 = 0.f;
      float a20 = 0.f, a21 = 0.f, a30 = 0.f, a31 = 0.f;
      #pragma unroll 4
      for (int n = 0; n < NNODE; ++n) {
        float4 s  = *(const float4*)&SC(e, n, hb);
        float2 ev = *(const float2*)(encG + (size_t)n * DIM + j2 * 2);
        a00 = fmaf(s.x, ev.x, a00); a01 = fmaf(s.x, ev.y, a01);
        a10 = fmaf(s.y, ev.x, a10); a11 = fmaf(s.y, ev.y, a11);
        a20 = fmaf(s.z, ev.x, a20); a21 = fmaf(s.z, ev.y, a21);
        a30 = fmaf(s.w, ev.x, a30); a31 = fmaf(s.w, ev.y, a31);
      }
      *(float2*)&ZR(e, hb + 0, j2 * 2) = make_float2(a00, a01);
      *(float2*)&ZR(e, hb + 1, j2 * 2) = make_float2(a10, a11);
      *(float2*)&ZR(e, hb + 2, j2 * 2) = make_float2(a20, a21);
      *(float2*)&ZR(e, hb + 3, j2 * 2) = make_float2(a30, a31);
    }
    __syncthreads();

    // PH5b: q3: attn chains (both elems), packed mv loads
    if (quad == 3) {
      int h = j >> 4;
      float C0 = 0.f, C1 = 0.f;
      #pragma unroll 8
      for (int t = 0; t < 32; ++t) {
        float4 z0 = *(const float4*)&ZR(0, h, t * 4);
        float4 z1 = *(const float4*)&ZR(1, h, t * 4);
        float4 wv = mvP[t * 128 + j];
        C0 = fmaf(z0.x, wv.x, C0); C0 = fmaf(z0.y, wv.y, C0);
        C0 = fmaf(z0.z, wv.z, C0); C0 = fmaf(z0.w, wv.w, C0);
        C1 = fmaf(z1.x, wv.x, C1); C1 = fmaf(z1.y, wv.y, C1);
        C1 = fmaf(z1.z, wv.z, C1); C1 = fmaf(z1.w, wv.w, C1);
      }
      S.attn[0][j] = C0; S.attn[1][j] = C1;
    }
    __syncthreads();

    // PH6: q1: op = attn @ F (both elems), packed F loads
    if (quad == 1) {
      const float4* xa = (const float4*)&S.attn[0][0];
      const float4* xb = (const float4*)&S.attn[1][0];
      float D0 = 0.f, D1 = 0.f;
      #pragma unroll 8
      for (int t = 0; t < 32; ++t) {
        float4 va = xa[t], vb = xb[t];
        float4 wv = FP[t * 128 + j];
        D0 = fmaf(va.x, wv.x, D0); D0 = fmaf(va.y, wv.y, D0);
        D0 = fmaf(va.z, wv.z, D0); D0 = fmaf(va.w, wv.w, D0);
        D1 = fmaf(vb.x, wv.x, D1); D1 = fmaf(vb.y, wv.y, D1);
        D1 = fmaf(vb.z, wv.z, D1); D1 = fmaf(vb.w, wv.w, D1);
      }
      S.op[0][j] = D0; S.op[1][j] = D1;
    }
    __syncthreads();

    // PH7: comp2 partials — enc from LDS (row-per-lane; global would be uncoalesced)
    {
      int qd = sub & 3, nq = sub >> 2;   // nq 0..63
      #pragma unroll
      for (int p = 0; p < 2; ++p) {
        int n = p * 64 + nq;
        if (n < NNODE) {
          float acc = 0.f;
          #pragma unroll
          for (int i4 = 0; i4 < 8; ++i4) {
            float4 ov = *(const float4*)&S.op[e][qd * 32 + i4 * 4];
            float4 e4 = *(const float4*)&EL(e, n, qd * 32 + i4 * 4);
            acc = fmaf(e4.x, ov.x, acc);
            acc = fmaf(e4.y, ov.y, acc);
            acc = fmaf(e4.z, ov.z, acc);
            acc = fmaf(e4.w, ov.w, acc);
          }
          SRED(e, n, qd) = acc;
        }
      }
    }
    __syncthreads();

    // PH8+ (merged PH7b/PH8/PH9-mask): per-elem wave computes logits, argmax,
    // logsumexp, state update AND mask/mask1 update — all in-wave, bit-exact order.
    if (sub < 64) {
      int lane = sub;
      // logits (was PH7b)
      float4 r0 = *(const float4*)&SRED(e, lane, 0);
      float tot0 = (r0.x + r0.y) + (r0.z + r0.w);
      float x0 = tanhf(tot0 * NORM_PROB) * 10.f;
      float v0 = (S.mask[e][lane] > 0.5f) ? NEG_INF : x0;
      float v1 = NEG_INF;
      if (lane < NNODE - 64) {
        float4 r1 = *(const float4*)&SRED(e, lane + 64, 0);
        float tot1 = (r1.x + r1.y) + (r1.z + r1.w);
        float x1 = tanhf(tot1 * NORM_PROB) * 10.f;
        v1 = (S.mask[e][lane + 64] > 0.5f) ? NEG_INF : x1;
      }
      // argmax (first-index ties)
      float bv; int bi;
      if (v1 > v0) { bv = v1; bi = lane + 64; } else { bv = v0; bi = lane; }
      #pragma unroll
      for (int o = 32; o > 0; o >>= 1) {
        float ov = __shfl_xor(bv, o, 64);
        int   oi = __shfl_xor(bi, o, 64);
        if (ov > bv || (ov == bv && oi < bi)) { bv = ov; bi = oi; }
      }
      // logsumexp
      float e0 = expf(v0 - bv);
      float e1 = (lane < NNODE - 64) ? expf(v1 - bv) : 0.f;
      float ss = e0 + e1;
      #pragma unroll
      for (int o = 32; o > 0; o >>= 1) ss += __shfl_xor(ss, o, 64);
      // is_done from PRE-update mask1
      int c = 0;
      if (lane >= 1 && S.mask1[e][lane] > 0.5f) c++;
      if (lane + 64 < NNODE && S.mask1[e][lane + 64] > 0.5f) c++;
      #pragma unroll
      for (int o = 32; o > 0; o >>= 1) c += __shfl_xor(c, o, 64);
      // new cap (wave-uniform; bi uniform after reduction)
      float newcap = (bi < 1) ? cap0 : (S.cap[e] - S.dem[e][bi]);
      if (lane == 0) {
        if (c < NNODE - 1) S.lp[e] += -logf(ss);
        d_out[(size_t)myb * NSTEP + step] = (float)bi;
        S.cap[e] = newcap;
        S.idx[e] = bi;
      }
      // mask1 + mask update with NEW cap (was PH9), incl. all-done depot reopen
      float m1a;
      if (lane == 0) m1a = (bi < 1) ? 1.f : 0.f;
      else           m1a = (lane == bi) ? 1.f : S.mask1[e][lane];
      float ma = (S.dem[e][lane] > newcap) ? 1.f : m1a;
      float m1b = 0.f, mb = 1.f;
      if (lane + 64 < NNODE) {
        m1b = (lane + 64 == bi) ? 1.f : S.mask1[e][lane + 64];
        mb  = (S.dem[e][lane + 64] > newcap) ? 1.f : m1b;
      }
      bool ok = (lane == 0) || (ma > 0.5f);
      if (lane + 64 < NNODE) ok = ok && (mb > 0.5f);
      bool alld = __all(ok);
      if (alld && lane == 0) ma = 0.f;
      S.mask1[e][lane] = m1a;
      S.mask[e][lane]  = ma;
      if (lane + 64 < NNODE) { S.mask1[e][lane + 64] = m1b; S.mask[e][lane + 64] = mb; }
    }
    __syncthreads();

    // PH9: new input row (from LDS enc)
    if (sub < 128) S.in_[e][sub] = EL(e, S.idx[e], sub);
    __syncthreads();
  }

  if (sub == 0) d_out[(size_t)BTOT * NSTEP + myb] = S.lp[e];
}

extern "C" void kernel_launch(void* const* d_in, const int* in_sizes, int n_in,
                              void* d_out, int out_size, void* d_ws, size_t ws_size,
                              hipStream_t stream) {
  const float* enc   = (const float*)d_in[0];
  const float* pool  = (const float*)d_in[1];
  const float* cap   = (const float*)d_in[2];
  const float* dem   = (const float*)d_in[3];
  const float* fc_w  = (const float*)d_in[7];
  const float* fc1_w = (const float*)d_in[8];
  const float* pk_w  = (const float*)d_in[9];
  const float* mw_w  = (const float*)d_in[10];
  const float* mk_w  = (const float*)d_in[11];
  const float* mv_w  = (const float*)d_in[12];
  const float* mfc_w = (const float*)d_in[13];
  float* out = (float*)d_out;
  float* ws  = (float*)d_ws;

  prep_weights<<<97, 256, 0, stream>>>(fc_w, fc1_w, mw_w, mv_w, mfc_w, pk_w, mk_w, ws);
  decoder_loop<<<BTOT / 2, 512, 0, stream>>>(enc, pool, cap, dem, ws, out);
}

// Round 12
// 12163.356 us; speedup vs baseline: 1.4497x; 1.4497x over previous
//
#include <hip/hip_runtime.h>

#define NNODE 101
#define DIM   128
#define NHEAD 8
#define NSTEP 150
#define BTOT  2048
#define ENCP  132          // padded enc row stride in LDS

// packed-weight ws layout (floats)
#define OFF_FCP   0
#define OFF_FC1P  16384
#define OFF_MWP   32768
#define OFF_MVP   49152
#define OFF_FP    65536
#define OFF_MKP   81920
#define OFF_FCC   98304
#define NORM_PROB 0.08838834764831845f

// One block = TWO batch elements, 512 threads (8 waves), 1 block/CU (LDS ~140 KB).
// R10 chassis (enc in LDS — R11's global-enc thrashed L2, FETCH 54->760 MB) +
// (a) PH3 remap: head-pair x 16-rows/wave -> 2-way (free) bank aliasing, 6 LDS
//     instrs per 32 MACs (was 10) — chains bit-exact;
// (b) narrow weight phases spread over more waves (PH1 4-quads, PH2/PH5b/PH6 2 quads);
// (c) R11's verified merged tail (logits+argmax+state+mask in one wave phase).
struct __align__(16) BS {
  float enc[2][NNODE * ENCP];           // 2 x 53328 B
  float in_[2][DIM], pl[2][DIM], dec[2][DIM], q[2][DIM], attn[2][DIM], op[2][DIM];
  float U[2][1888];                     // QK/ZR: h*132+i ; CMP: 1056+h*104+n
  float sc[2][1212];                    // SC: n*12+h ; SRED: n*12+k
  float mask[2][NNODE], mask1[2][NNODE], dem[2][NNODE];
  float cap[2], lp[2];
  int   idx[2];
};

#define EL(e,n,i)     S.enc[e][(n)*ENCP + (i)]
#define QK(e,h,i)     S.U[e][(h)*132 + (i)]
#define ZR(e,h,i)     S.U[e][(h)*132 + (i)]
#define CMP(e,h,n)    S.U[e][1056 + (h)*104 + (n)]
#define SC(e,n,h)     S.sc[e][(n)*12 + (h)]
#define SRED(e,n,k)   S.sc[e][(n)*12 + (k)]

// Pack all weights as float4 panels: P[i4*128 + j] = {wT[i4*4+0][j], .., wT[i4*4+3][j]}
__global__ void prep_weights(const float* __restrict__ fc_w,
                             const float* __restrict__ fc1_w,
                             const float* __restrict__ mw_w,
                             const float* __restrict__ mv_w,
                             const float* __restrict__ mfc_w,
                             const float* __restrict__ pk_w,
                             const float* __restrict__ mk_w,
                             float* __restrict__ ws) {
  int x = blockIdx.x * 256 + threadIdx.x;
  if (x < 4096) {                      // fcP
    int i4 = x >> 7, j = x & 127;
    float4 v = make_float4(fc_w[j * 129 + i4 * 4 + 0], fc_w[j * 129 + i4 * 4 + 1],
                           fc_w[j * 129 + i4 * 4 + 2], fc_w[j * 129 + i4 * 4 + 3]);
    *(float4*)&ws[OFF_FCP + x * 4] = v; return;
  }
  x -= 4096;
  if (x < 4096) {                      // fc1P
    int i4 = x >> 7, j = x & 127;
    float4 v = make_float4(fc1_w[j * 128 + i4 * 4 + 0], fc1_w[j * 128 + i4 * 4 + 1],
                           fc1_w[j * 128 + i4 * 4 + 2], fc1_w[j * 128 + i4 * 4 + 3]);
    *(float4*)&ws[OFF_FC1P + x * 4] = v; return;
  }
  x -= 4096;
  if (x < 4096) {                      // mwP
    int i4 = x >> 7, j = x & 127;
    float4 v = make_float4(mw_w[j * 128 + i4 * 4 + 0], mw_w[j * 128 + i4 * 4 + 1],
                           mw_w[j * 128 + i4 * 4 + 2], mw_w[j * 128 + i4 * 4 + 3]);
    *(float4*)&ws[OFF_MWP + x * 4] = v; return;
  }
  x -= 4096;
  if (x < 4096) {                      // mvP
    int i4 = x >> 7, j = x & 127;
    float4 v = make_float4(mv_w[j * 128 + i4 * 4 + 0], mv_w[j * 128 + i4 * 4 + 1],
                           mv_w[j * 128 + i4 * 4 + 2], mv_w[j * 128 + i4 * 4 + 3]);
    *(float4*)&ws[OFF_MVP + x * 4] = v; return;
  }
  x -= 4096;
  if (x < 4096) {                      // FP : F[i2][j] = sum_d mfc[d][i2]*pk[d][j]
    int i4 = x >> 7, j = x & 127;
    float a[4] = {0.f, 0.f, 0.f, 0.f};
    for (int d = 0; d < 128; ++d) {
      float p = pk_w[d * 128 + j];
      a[0] = fmaf(mfc_w[d * 128 + i4 * 4 + 0], p, a[0]);
      a[1] = fmaf(mfc_w[d * 128 + i4 * 4 + 1], p, a[1]);
      a[2] = fmaf(mfc_w[d * 128 + i4 * 4 + 2], p, a[2]);
      a[3] = fmaf(mfc_w[d * 128 + i4 * 4 + 3], p, a[3]);
    }
    *(float4*)&ws[OFF_FP + x * 4] = make_float4(a[0], a[1], a[2], a[3]); return;
  }
  x -= 4096;
  if (x < 4096) {                      // mkP
    int hk = x >> 7, j = x & 127;
    int h = hk >> 2, k4 = hk & 3;
    float4 v = make_float4(mk_w[(h * 16 + k4 * 4 + 0) * 128 + j],
                           mk_w[(h * 16 + k4 * 4 + 1) * 128 + j],
                           mk_w[(h * 16 + k4 * 4 + 2) * 128 + j],
                           mk_w[(h * 16 + k4 * 4 + 3) * 128 + j]);
    *(float4*)&ws[OFF_MKP + x * 4] = v; return;
  }
  x -= 4096;
  if (x < 128) ws[OFF_FCC + x] = fc_w[x * 129 + 128];   // fc cap column
}

__global__ __launch_bounds__(512, 2) void decoder_loop(
    const float* __restrict__ enc, const float* __restrict__ pool,
    const float* __restrict__ capcity, const float* __restrict__ demand,
    const float* __restrict__ ws, float* __restrict__ d_out) {
  const float4* fcP  = (const float4*)(ws + OFF_FCP);
  const float4* fc1P = (const float4*)(ws + OFF_FC1P);
  const float4* mwP  = (const float4*)(ws + OFF_MWP);
  const float4* mvP  = (const float4*)(ws + OFF_MVP);
  const float4* FP   = (const float4*)(ws + OFF_FP);
  const float4* mkP  = (const float4*)(ws + OFF_MKP);

  __shared__ BS S;

  const int tl   = threadIdx.x;       // 0..511
  const int j    = tl & 127;
  const int quad = tl >> 7;           // 0..3, wave-uniform
  const int e    = quad >> 1;         // elem for per-elem (enc) phases
  const int sub  = tl & 255;          // 0..255 within elem group
  const int b    = blockIdx.x;
  const int myb  = 2 * b + e;
  const float NEG_INF = -__builtin_inff();
  const float cap0 = capcity[0];

  // ---- stage both enc slices into LDS ----
  for (int ee = 0; ee < 2; ++ee) {
    const float* src = enc + (size_t)(2 * b + ee) * NNODE * DIM;
    for (int x = tl; x < NNODE * 32; x += 512) {
      int n = x >> 5, c = x & 31;
      *(float4*)&EL(ee, n, c * 4) = *(const float4*)(src + (size_t)n * DIM + c * 4);
    }
  }
  __syncthreads();

  // ---- init carry ----
  if (sub < 128) {
    S.in_[e][sub] = EL(e, 0, sub);
    S.pl[e][sub]  = pool[(size_t)myb * DIM + sub];
  }
  if (sub < NNODE) S.dem[e][sub] = demand[(size_t)myb * NNODE + sub];
  if (sub == 0) { S.cap[e] = capcity[myb]; S.lp[e] = 0.f; S.idx[e] = 0; }
  __syncthreads();
  if (sub < NNODE) {
    float v1 = (sub == 0) ? 1.f : 0.f;
    S.mask1[e][sub] = v1;
    S.mask[e][sub] = (S.dem[e][sub] > S.cap[e]) ? 1.f : v1;
  }
  __syncthreads();
  if (sub < 64) {
    bool ok = (sub == 0) || (S.mask[e][sub] > 0.5f);
    if (sub + 64 < NNODE) ok = ok && (S.mask[e][sub + 64] > 0.5f);
    bool alld = __all(ok);
    if (alld && sub == 0) S.mask[e][0] = 0.f;
  }
  __syncthreads();

  for (int step = 0; step < NSTEP; ++step) {
    const float capR0 = S.cap[0], capR1 = S.cap[1];

    // PH1: 4-way spread: q0: fc e0; q1: fc e1; q2: fc1 e0; q3: fc1 e1. One chain/thread.
    {
      float A = 0.f;
      if (quad < 2) {
        const float4* x4 = (const float4*)&S.in_[quad][0];
        #pragma unroll 8
        for (int t = 0; t < 32; ++t) {
          float4 v = x4[t];
          float4 wv = fcP[t * 128 + j];
          A = fmaf(v.x, wv.x, A); A = fmaf(v.y, wv.y, A);
          A = fmaf(v.z, wv.z, A); A = fmaf(v.w, wv.w, A);
        }
        A = fmaf(quad == 0 ? capR0 : capR1, ws[OFF_FCC + j], A);
      } else {
        const float4* x4 = (const float4*)&S.pl[quad - 2][0];
        #pragma unroll 8
        for (int t = 0; t < 32; ++t) {
          float4 v = x4[t];
          float4 wv = fc1P[t * 128 + j];
          A = fmaf(v.x, wv.x, A); A = fmaf(v.y, wv.y, A);
          A = fmaf(v.z, wv.z, A); A = fmaf(v.w, wv.w, A);
        }
      }
      __syncthreads();
      if (quad < 2) S.dec[quad][j] = A;
      else          S.pl[quad - 2][j] = A;
    }
    __syncthreads();

    // PH2: q2: Q e0; q3: Q e1. One chain/thread; (dec+pl) inline (same float value).
    if (quad >= 2) {
      int e2 = quad - 2;
      const float4* d4 = (const float4*)&S.dec[e2][0];
      const float4* p4 = (const float4*)&S.pl[e2][0];
      float B = 0.f;
      #pragma unroll 8
      for (int t = 0; t < 32; ++t) {
        float4 a = d4[t], p = p4[t];
        float4 wv = mwP[t * 128 + j];
        B = fmaf(a.x + p.x, wv.x, B); B = fmaf(a.y + p.y, wv.y, B);
        B = fmaf(a.z + p.z, wv.z, B); B = fmaf(a.w + p.w, wv.w, B);
      }
      S.q[e2][j] = B;
    }
    __syncthreads();

    // PH2b: quad -> heads {2q, 2q+1}; each thread computes BOTH elems per head.
    {
      const float4* q40 = (const float4*)&S.q[0][0];
      const float4* q41 = (const float4*)&S.q[1][0];
      #pragma unroll
      for (int hh = 0; hh < 2; ++hh) {
        int h = quad * 2 + hh;
        const float4* mp = mkP + (h * 4) * 128 + j;
        float4 M0 = mp[0], M1 = mp[128], M2 = mp[256], M3 = mp[384];
        float4 qa0 = q40[h*4], qb0 = q40[h*4+1], qc0 = q40[h*4+2], qd0 = q40[h*4+3];
        float4 qa1 = q41[h*4], qb1 = q41[h*4+1], qc1 = q41[h*4+2], qd1 = q41[h*4+3];
        float acc0 = 0.f, acc1 = 0.f;
        acc0 = fmaf(qa0.x, M0.x, acc0); acc0 = fmaf(qa0.y, M0.y, acc0);
        acc0 = fmaf(qa0.z, M0.z, acc0); acc0 = fmaf(qa0.w, M0.w, acc0);
        acc0 = fmaf(qb0.x, M1.x, acc0); acc0 = fmaf(qb0.y, M1.y, acc0);
        acc0 = fmaf(qb0.z, M1.z, acc0); acc0 = fmaf(qb0.w, M1.w, acc0);
        acc0 = fmaf(qc0.x, M2.x, acc0); acc0 = fmaf(qc0.y, M2.y, acc0);
        acc0 = fmaf(qc0.z, M2.z, acc0); acc0 = fmaf(qc0.w, M2.w, acc0);
        acc0 = fmaf(qd0.x, M3.x, acc0); acc0 = fmaf(qd0.y, M3.y, acc0);
        acc0 = fmaf(qd0.z, M3.z, acc0); acc0 = fmaf(qd0.w, M3.w, acc0);
        acc1 = fmaf(qa1.x, M0.x, acc1); acc1 = fmaf(qa1.y, M0.y, acc1);
        acc1 = fmaf(qa1.z, M0.z, acc1); acc1 = fmaf(qa1.w, M0.w, acc1);
        acc1 = fmaf(qb1.x, M1.x, acc1); acc1 = fmaf(qb1.y, M1.y, acc1);
        acc1 = fmaf(qb1.z, M1.z, acc1); acc1 = fmaf(qb1.w, M1.w, acc1);
        acc1 = fmaf(qc1.x, M2.x, acc1); acc1 = fmaf(qc1.y, M2.y, acc1);
        acc1 = fmaf(qc1.z, M2.z, acc1); acc1 = fmaf(qc1.w, M2.w, acc1);
        acc1 = fmaf(qd1.x, M3.x, acc1); acc1 = fmaf(qd1.y, M3.y, acc1);
        acc1 = fmaf(qd1.z, M3.z, acc1); acc1 = fmaf(qd1.w, M3.w, acc1);
        QK(0, h, j) = acc0;
        QK(1, h, j) = acc1;
      }
    }
    __syncthreads();

    // PH3 v3: 2 waves/elem (sub<128). Thread = (h2 = sub&3 -> head pair, nb = sub>>2).
    // Per i4: 2 qk b128 (4 addrs, broadcast, distinct quads) + 4 enc b128
    // (16 rows/instr -> 2 rows/bank-quad = FREE). 32 MACs / 6 LDS instrs.
    // Per-(h,n) chains: i4 ascending, x->y->z->w, single acc — bit-exact vs R10.
    if (sub < 128) {
      int h2 = sub & 3, nb = sub >> 2;   // h2 0..3, nb 0..31
      int ha = h2 * 2, hb2 = h2 * 2 + 1;
      float accA[4] = {0.f, 0.f, 0.f, 0.f};
      float accB[4] = {0.f, 0.f, 0.f, 0.f};
      #pragma unroll 4
      for (int i4 = 0; i4 < 32; ++i4) {
        float4 qA = *(const float4*)&QK(e, ha,  i4 * 4);
        float4 qB = *(const float4*)&QK(e, hb2, i4 * 4);
        #pragma unroll
        for (int p = 0; p < 4; ++p) {
          int n = p * 32 + nb;
          if (n < NNODE) {
            float4 e4 = *(const float4*)&EL(e, n, i4 * 4);
            accA[p] = fmaf(e4.x, qA.x, accA[p]);
            accA[p] = fmaf(e4.y, qA.y, accA[p]);
            accA[p] = fmaf(e4.z, qA.z, accA[p]);
            accA[p] = fmaf(e4.w, qA.w, accA[p]);
            accB[p] = fmaf(e4.x, qB.x, accB[p]);
            accB[p] = fmaf(e4.y, qB.y, accB[p]);
            accB[p] = fmaf(e4.z, qB.z, accB[p]);
            accB[p] = fmaf(e4.w, qB.w, accB[p]);
          }
        }
      }
      #pragma unroll
      for (int p = 0; p < 4; ++p) {
        int n = p * 32 + nb;
        if (n < NNODE) {
          float mk = S.mask[e][n];
          CMP(e, ha,  n) = (mk > 0.5f) ? NEG_INF : 0.25f * accA[p];
          CMP(e, hb2, n) = (mk > 0.5f) ? NEG_INF : 0.25f * accB[p];
        }
      }
    }
    __syncthreads();

    // PH4: softmax; 8 waves = (elem, head pair)
    {
      int w = tl >> 6, lane = tl & 63;
      int ee = w >> 2, hb = (w & 3) * 2;
      #pragma unroll
      for (int hh = 0; hh < 2; ++hh) {
        int h = hb + hh;
        float v0 = CMP(ee, h, lane);
        float v1 = (lane < NNODE - 64) ? CMP(ee, h, lane + 64) : NEG_INF;
        float m = fmaxf(v0, v1);
        #pragma unroll
        for (int o = 32; o > 0; o >>= 1) m = fmaxf(m, __shfl_xor(m, o, 64));
        float e0 = expf(v0 - m);
        float e1 = (lane < NNODE - 64) ? expf(v1 - m) : 0.f;
        float ss = e0 + e1;
        #pragma unroll
        for (int o = 32; o > 0; o >>= 1) ss += __shfl_xor(ss, o, 64);
        SC(ee, lane, h) = e0 / ss;
        if (lane < NNODE - 64) SC(ee, lane + 64, h) = e1 / ss;
      }
    }
    __syncthreads();

    // PH5: 2 waves per elem. Thread = (hq, j2): 4 heads x 2 dims.
    // sc b128 broadcast + enc b64 consecutive (conflict-free). n ascending — bit-exact.
    if (sub < 128) {
      int j2 = sub & 63, hq = sub >> 6;
      int hb = hq * 4;
      float a00 = 0.f, a01 = 0.f, a10 = 0.f, a11 = 0.f;
      float a20 = 0.f, a21 = 0.f, a30 = 0.f, a31 = 0.f;
      #pragma unroll 4
      for (int n = 0; n < NNODE; ++n) {
        float4 s  = *(const float4*)&SC(e, n, hb);
        float2 ev = *(const float2*)&EL(e, n, j2 * 2);
        a00 = fmaf(s.x, ev.x, a00); a01 = fmaf(s.x, ev.y, a01);
        a10 = fmaf(s.y, ev.x, a10); a11 = fmaf(s.y, ev.y, a11);
        a20 = fmaf(s.z, ev.x, a20); a21 = fmaf(s.z, ev.y, a21);
        a30 = fmaf(s.w, ev.x, a30); a31 = fmaf(s.w, ev.y, a31);
      }
      *(float2*)&ZR(e, hb + 0, j2 * 2) = make_float2(a00, a01);
      *(float2*)&ZR(e, hb + 1, j2 * 2) = make_float2(a10, a11);
      *(float2*)&ZR(e, hb + 2, j2 * 2) = make_float2(a20, a21);
      *(float2*)&ZR(e, hb + 3, j2 * 2) = make_float2(a30, a31);
    }
    __syncthreads();

    // PH5b: q2: attn e0; q3: attn e1. One chain/thread.
    if (quad >= 2) {
      int e2 = quad - 2;
      int h = j >> 4;
      float C = 0.f;
      #pragma unroll 8
      for (int t = 0; t < 32; ++t) {
        float4 z = *(const float4*)&ZR(e2, h, t * 4);
        float4 wv = mvP[t * 128 + j];
        C = fmaf(z.x, wv.x, C); C = fmaf(z.y, wv.y, C);
        C = fmaf(z.z, wv.z, C); C = fmaf(z.w, wv.w, C);
      }
      S.attn[e2][j] = C;
    }
    __syncthreads();

    // PH6: q0: op e0; q1: op e1. One chain/thread.
    if (quad < 2) {
      const float4* x4 = (const float4*)&S.attn[quad][0];
      float D = 0.f;
      #pragma unroll 8
      for (int t = 0; t < 32; ++t) {
        float4 v = x4[t];
        float4 wv = FP[t * 128 + j];
        D = fmaf(v.x, wv.x, D); D = fmaf(v.y, wv.y, D);
        D = fmaf(v.z, wv.z, D); D = fmaf(v.w, wv.w, D);
      }
      S.op[quad][j] = D;
    }
    __syncthreads();

    // PH7: comp2 partials — per elem, enc from LDS (bit-exact mapping)
    {
      int qd = sub & 3, nq = sub >> 2;   // nq 0..63
      #pragma unroll
      for (int p = 0; p < 2; ++p) {
        int n = p * 64 + nq;
        if (n < NNODE) {
          float acc = 0.f;
          #pragma unroll
          for (int i4 = 0; i4 < 8; ++i4) {
            float4 ov = *(const float4*)&S.op[e][qd * 32 + i4 * 4];
            float4 e4 = *(const float4*)&EL(e, n, qd * 32 + i4 * 4);
            acc = fmaf(e4.x, ov.x, acc);
            acc = fmaf(e4.y, ov.y, acc);
            acc = fmaf(e4.z, ov.z, acc);
            acc = fmaf(e4.w, ov.w, acc);
          }
          SRED(e, n, qd) = acc;
        }
      }
    }
    __syncthreads();

    // PH8 merged tail (R11-verified): logits, argmax, logsumexp, state, mask update.
    if (sub < 64) {
      int lane = sub;
      float4 r0 = *(const float4*)&SRED(e, lane, 0);
      float tot0 = (r0.x + r0.y) + (r0.z + r0.w);
      float x0 = tanhf(tot0 * NORM_PROB) * 10.f;
      float v0 = (S.mask[e][lane] > 0.5f) ? NEG_INF : x0;
      float v1 = NEG_INF;
      if (lane < NNODE - 64) {
        float4 r1 = *(const float4*)&SRED(e, lane + 64, 0);
        float tot1 = (r1.x + r1.y) + (r1.z + r1.w);
        float x1 = tanhf(tot1 * NORM_PROB) * 10.f;
        v1 = (S.mask[e][lane + 64] > 0.5f) ? NEG_INF : x1;
      }
      float bv; int bi;
      if (v1 > v0) { bv = v1; bi = lane + 64; } else { bv = v0; bi = lane; }
      #pragma unroll
      for (int o = 32; o > 0; o >>= 1) {
        float ov = __shfl_xor(bv, o, 64);
        int   oi = __shfl_xor(bi, o, 64);
        if (ov > bv || (ov == bv && oi < bi)) { bv = ov; bi = oi; }
      }
      float e0 = expf(v0 - bv);
      float e1 = (lane < NNODE - 64) ? expf(v1 - bv) : 0.f;
      float ss = e0 + e1;
      #pragma unroll
      for (int o = 32; o > 0; o >>= 1) ss += __shfl_xor(ss, o, 64);
      int c = 0;
      if (lane >= 1 && S.mask1[e][lane] > 0.5f) c++;
      if (lane + 64 < NNODE && S.mask1[e][lane + 64] > 0.5f) c++;
      #pragma unroll
      for (int o = 32; o > 0; o >>= 1) c += __shfl_xor(c, o, 64);
      float newcap = (bi < 1) ? cap0 : (S.cap[e] - S.dem[e][bi]);
      if (lane == 0) {
        if (c < NNODE - 1) S.lp[e] += -logf(ss);
        d_out[(size_t)myb * NSTEP + step] = (float)bi;
        S.cap[e] = newcap;
        S.idx[e] = bi;
      }
      float m1a;
      if (lane == 0) m1a = (bi < 1) ? 1.f : 0.f;
      else           m1a = (lane == bi) ? 1.f : S.mask1[e][lane];
      float ma = (S.dem[e][lane] > newcap) ? 1.f : m1a;
      float m1b = 0.f, mb = 1.f;
      if (lane + 64 < NNODE) {
        m1b = (lane + 64 == bi) ? 1.f : S.mask1[e][lane + 64];
        mb  = (S.dem[e][lane + 64] > newcap) ? 1.f : m1b;
      }
      bool ok = (lane == 0) || (ma > 0.5f);
      if (lane + 64 < NNODE) ok = ok && (mb > 0.5f);
      bool alld = __all(ok);
      if (alld && lane == 0) ma = 0.f;
      S.mask1[e][lane] = m1a;
      S.mask[e][lane]  = ma;
      if (lane + 64 < NNODE) { S.mask1[e][lane + 64] = m1b; S.mask[e][lane + 64] = mb; }
    }
    __syncthreads();

    // PH9: new input row (from LDS enc)
    if (sub < 128) S.in_[e][sub] = EL(e, S.idx[e], sub);
    __syncthreads();
  }

  if (sub == 0) d_out[(size_t)BTOT * NSTEP + myb] = S.lp[e];
}

extern "C" void kernel_launch(void* const* d_in, const int* in_sizes, int n_in,
                              void* d_out, int out_size, void* d_ws, size_t ws_size,
                              hipStream_t stream) {
  const float* enc   = (const float*)d_in[0];
  const float* pool  = (const float*)d_in[1];
  const float* cap   = (const float*)d_in[2];
  const float* dem   = (const float*)d_in[3];
  const float* fc_w  = (const float*)d_in[7];
  const float* fc1_w = (const float*)d_in[8];
  const float* pk_w  = (const float*)d_in[9];
  const float* mw_w  = (const float*)d_in[10];
  const float* mk_w  = (const float*)d_in[11];
  const float* mv_w  = (const float*)d_in[12];
  const float* mfc_w = (const float*)d_in[13];
  float* out = (float*)d_out;
  float* ws  = (float*)d_ws;

  prep_weights<<<97, 256, 0, stream>>>(fc_w, fc1_w, mw_w, mv_w, mfc_w, pk_w, mk_w, ws);
  decoder_loop<<<BTOT / 2, 512, 0, stream>>>(enc, pool, cap, dem, ws, out);
}